// Round 10
// baseline (186.572 us; speedup 1.0000x reference)
//
#include <hip/hip_runtime.h>

// DistributionLoss: local 7x7xC std (zero-padded) of two [16,3,512,512] fp32
// tensors, smooth-L1 mean between std maps -> scalar.
//
// R10: BARRIER-FREE wave-private rolling march. Each wave owns a 64x32
// strip; lanes = (4 row-slots r) x (16 colgroups c). Per 4-row step k:
//   1) h/g for rows y0-3+4k+r from in-flight loads (both inputs), write to
//      a wave-private 12-row LDS ring (no __syncthreads anywhere: wave
//      lockstep + lgkmcnt ordering).
//   2) issue next step's 18 float4 loads (consumed ~250 VALU later).
//   3) vertical 7-tap from ring + std + fused smooth-L1 for output rows
//      y0+4k-6+r (masked by cndmask; ring garbage at k=0 NaN-safe).
// Zero barriers -> no vmcnt(0) drains (the R7-R9 55us wall); waves slip
// freely. Dynamic k-loop (unroll 1) keeps VGPR bounded (R4-R6 lesson).

#define K     7
#define PAD   3
#define RING  12
#define LDSW  68          // ring row stride: 4-bank skew per slot
#define NWAVE 2
#define NT    (NWAVE * 64)

struct T9 { float4 A0, B0, C0, A1, B1, C1, A2, B2, C2; };

__device__ __forceinline__ float4 ld4(const float* p) { return *(const float4*)p; }

__device__ __forceinline__ float4 add3(float4 a, float4 b, float4 c) {
    return make_float4(a.x + b.x + c.x, a.y + b.y + c.y,
                       a.z + b.z + c.z, a.w + b.w + c.w);
}
__device__ __forceinline__ float4 sq3(float4 a, float4 b, float4 c) {
    return make_float4(fmaf(a.x, a.x, fmaf(b.x, b.x, c.x * c.x)),
                       fmaf(a.y, a.y, fmaf(b.y, b.y, c.y * c.y)),
                       fmaf(a.z, a.z, fmaf(b.z, b.z, c.z * c.z)),
                       fmaf(a.w, a.w, fmaf(b.w, b.w, c.w * c.w)));
}

__device__ __forceinline__ T9 load9(const float* rowp, size_t plane,
                                    bool lOK, bool rOK) {
    const float4 z4 = make_float4(0.f, 0.f, 0.f, 0.f);
    const float* r1 = rowp + plane;
    const float* r2 = r1 + plane;
    T9 t;
    t.A0 = lOK ? ld4(rowp - 4) : z4;  t.B0 = ld4(rowp);  t.C0 = rOK ? ld4(rowp + 4) : z4;
    t.A1 = lOK ? ld4(r1 - 4)   : z4;  t.B1 = ld4(r1);    t.C1 = rOK ? ld4(r1 + 4)   : z4;
    t.A2 = lOK ? ld4(r2 - 4)   : z4;  t.B2 = ld4(r2);    t.C2 = rOK ? ld4(r2 + 4)   : z4;
    return t;
}

__device__ __forceinline__ void hg(const T9& t, float m, float4& h, float4& g) {
    float4 tl = add3(t.A0, t.A1, t.A2);
    float4 tm = add3(t.B0, t.B1, t.B2);
    float4 tr = add3(t.C0, t.C1, t.C2);
    float4 ul = sq3(t.A0, t.A1, t.A2);
    float4 um = sq3(t.B0, t.B1, t.B2);
    float4 ur = sq3(t.C0, t.C1, t.C2);
    float h0 = tl.y + tl.z + tl.w + tm.x + tm.y + tm.z + tm.w;
    float h1 = h0 - tl.y + tr.x;
    float h2 = h1 - tl.z + tr.y;
    float h3 = h2 - tl.w + tr.z;
    float g0 = ul.y + ul.z + ul.w + um.x + um.y + um.z + um.w;
    float g1 = g0 - ul.y + ur.x;
    float g2 = g1 - ul.z + ur.y;
    float g3 = g2 - ul.w + ur.z;
    h = make_float4(h0 * m, h1 * m, h2 * m, h3 * m);
    g = make_float4(g0 * m, g1 * m, g2 * m, g3 * m);
}

__global__ __launch_bounds__(NT, 2) void dist_loss_kernel(
    const float* __restrict__ pred,
    const float* __restrict__ tgt,
    float* __restrict__ out)
{
    constexpr int   H = 512, W = 512;
    constexpr float INV_N     = 1.0f / 147.0f;                   // 1/(3*7*7)
    constexpr float INV_TOTAL = 1.0f / (16.0f * 512.0f * 512.0f);

    __shared__ float ring[NWAVE][4][RING][LDSW];   // hP,gP,hT,gT

    const int tid  = threadIdx.x;
    const int wv   = tid >> 6;
    const int lane = tid & 63;
    const int r    = lane >> 4;          // row slot 0..3
    const int c    = lane & 15;          // colgroup 0..15

    const int colstrip = blockIdx.x;                 // 0..7
    const int rowstrip = blockIdx.y * NWAVE + wv;    // 0..15 (pair shares halo)
    const int b        = blockIdx.z;

    const size_t plane = (size_t)H * W;
    const int    x0l   = colstrip * 64 + c * 4;
    const int    y0    = rowstrip * 32;
    const bool   lOK   = (x0l > 0);
    const bool   rOK   = (x0l < 508);

    const float* bp = pred + (size_t)b * 3 * plane + x0l;
    const float* bt = tgt  + (size_t)b * 3 * plane + x0l;

    float acc = 0.0f;
    int   sb  = 0;                        // ring write base: 0,4,8,0,...

    // prologue: loads for step 0 (rows y0-3+r)
    int   hyv = y0 - PAD + r;
    float m   = ((unsigned)hyv < (unsigned)H) ? 1.0f : 0.0f;
    int   gyc = min(max(hyv, 0), H - 1);
    T9 xp = load9(bp + (size_t)gyc * W, plane, lOK, rOK);
    T9 xt = load9(bt + (size_t)gyc * W, plane, lOK, rOK);

    #pragma unroll 1
    for (int k = 0; k < 10; ++k) {
        // ---- 1) h/g from in-flight loads, write wave-private ring
        float4 hP, gP, hT, gT;
        hg(xp, m, hP, gP);
        hg(xt, m, hT, gT);
        const int sw = sb + r;            // sb in {0,4,8}, r<4 -> no wrap
        *(float4*)&ring[wv][0][sw][c * 4] = hP;
        *(float4*)&ring[wv][1][sw][c * 4] = gP;
        *(float4*)&ring[wv][2][sw][c * 4] = hT;
        *(float4*)&ring[wv][3][sw][c * 4] = gT;

        // ---- 2) issue next step's loads (k=9's issue is clamped/wasted)
        hyv = y0 - PAD + 4 * (k + 1) + r;
        m   = ((unsigned)hyv < (unsigned)H) ? 1.0f : 0.0f;
        gyc = min(max(hyv, 0), H - 1);
        xp  = load9(bp + (size_t)gyc * W, plane, lOK, rOK);
        xt  = load9(bt + (size_t)gyc * W, plane, lOK, rOK);

        // ---- 3) vertical 7-tap from ring + std + fused smooth-L1
        int rb = sb + r + 6;  rb -= (rb >= RING) ? RING : 0;
        float4 SP = make_float4(0.f, 0.f, 0.f, 0.f);
        float4 QP = SP, ST = SP, QT = SP;
        int s = rb;
        #pragma unroll
        for (int j = 0; j < K; ++j) {
            float4 a = *(const float4*)&ring[wv][0][s][c * 4];
            float4 d = *(const float4*)&ring[wv][1][s][c * 4];
            float4 e = *(const float4*)&ring[wv][2][s][c * 4];
            float4 f = *(const float4*)&ring[wv][3][s][c * 4];
            SP.x += a.x; SP.y += a.y; SP.z += a.z; SP.w += a.w;
            QP.x += d.x; QP.y += d.y; QP.z += d.z; QP.w += d.w;
            ST.x += e.x; ST.y += e.y; ST.z += e.z; ST.w += e.w;
            QT.x += f.x; QT.y += f.y; QT.z += f.z; QT.w += f.w;
            s = (s == RING - 1) ? 0 : s + 1;
        }

        const int  oy    = y0 + 4 * k - 6 + r;
        const bool valid = ((unsigned)(oy - y0) < 32u);

        #define LOSS1(sp, qp, st, qt, dest)                                   \
            {                                                                 \
                float mup = (sp) * INV_N;                                     \
                float vp  = fmaf(-mup, mup, (qp) * INV_N);                    \
                float mut = (st) * INV_N;                                     \
                float vt  = fmaf(-mut, mut, (qt) * INV_N);                    \
                float d   = sqrtf(vp + 1e-8f) - sqrtf(vt + 1e-8f);            \
                float ad  = fabsf(d);                                         \
                dest = (ad < 1.0f) ? 0.5f * d * d : (ad - 0.5f);              \
            }
        float l0, l1, l2, l3;
        LOSS1(SP.x, QP.x, ST.x, QT.x, l0);
        LOSS1(SP.y, QP.y, ST.y, QT.y, l1);
        LOSS1(SP.z, QP.z, ST.z, QT.z, l2);
        LOSS1(SP.w, QP.w, ST.w, QT.w, l3);
        #undef LOSS1
        acc += valid ? (l0 + l1 + l2 + l3) : 0.0f;   // cndmask: NaN-safe

        sb += 4;  sb = (sb == RING) ? 0 : sb;
    }

    // ---- wave-level reduction, one atomic per wave (no barriers)
    #pragma unroll
    for (int off = 32; off > 0; off >>= 1)
        acc += __shfl_down(acc, off, 64);
    if (lane == 0)
        atomicAdd(out, acc * INV_TOTAL);
}

extern "C" void kernel_launch(void* const* d_in, const int* in_sizes, int n_in,
                              void* d_out, int out_size, void* d_ws, size_t ws_size,
                              hipStream_t stream) {
    const float* pred = (const float*)d_in[0];
    const float* tgt  = (const float*)d_in[1];
    float* out = (float*)d_out;

    hipMemsetAsync(out, 0, sizeof(float), stream);

    // 8 colstrips x 8 rowstrip-pairs x 16 batches = 1024 blocks of 128 thr
    dim3 grid(8, 16 / NWAVE, 16);
    dist_loss_kernel<<<grid, NT, 0, stream>>>(pred, tgt, out);
}

// Round 11
// 168.229 us; speedup vs baseline: 1.1090x; 1.1090x over previous
//
#include <hip/hip_runtime.h>

// DistributionLoss: local 7x7xC std (zero-padded) of two [16,3,512,512] fp32
// tensors, smooth-L1 mean between std maps -> scalar.
//
// R11: ONE-barrier blocks + max block churn.
//  - 64x16 output tile; phase A stages BOTH inputs' horizontal 7-tap (h,g)
//    into LDS (704 tasks, 9 float4 loads each, loads consumed in-iteration
//    so the compiler keeps them in flight naturally - R4-R10 lesson: any
//    cross-phase register pipelining gets sunk or spilled).
//  - Exactly ONE __syncthreads per block; phase B does vertical 7-tap +
//    std for both inputs + fused smooth-L1, then the block retires.
//  - 4096 short-lived blocks; 24 KB LDS -> 6 blocks/CU co-resident
//    (launch_bounds(256,6) caps VGPR at 85). Steady state: ~5 blocks/CU
//    issuing loads while 1 drains its barrier -> latency hidden by churn.

#define K     7
#define PAD   3
#define TSX   64
#define TSY   16
#define HR    (TSY + K - 1)     // 22 halo rows
#define LDSW  68                // LDS row stride (floats)
#define NT    256
#define NTH   (HR * 16)         // 352 tasks per input
#define NTASK (NTH * 2)         // 704 total

struct T9 { float4 A0, B0, C0, A1, B1, C1, A2, B2, C2; };

__device__ __forceinline__ float4 ld4(const float* p) { return *(const float4*)p; }

__device__ __forceinline__ float4 add3(float4 a, float4 b, float4 c) {
    return make_float4(a.x + b.x + c.x, a.y + b.y + c.y,
                       a.z + b.z + c.z, a.w + b.w + c.w);
}
__device__ __forceinline__ float4 sq3(float4 a, float4 b, float4 c) {
    return make_float4(fmaf(a.x, a.x, fmaf(b.x, b.x, c.x * c.x)),
                       fmaf(a.y, a.y, fmaf(b.y, b.y, c.y * c.y)),
                       fmaf(a.z, a.z, fmaf(b.z, b.z, c.z * c.z)),
                       fmaf(a.w, a.w, fmaf(b.w, b.w, c.w * c.w)));
}

__global__ __launch_bounds__(NT, 6) void dist_loss_kernel(
    const float* __restrict__ pred,
    const float* __restrict__ tgt,
    float* __restrict__ out)
{
    constexpr int   H = 512, W = 512;
    constexpr float INV_N     = 1.0f / 147.0f;                   // 1/(3*7*7)
    constexpr float INV_TOTAL = 1.0f / (16.0f * 512.0f * 512.0f);

    __shared__ float sh_s[2][HR][LDSW];   // horizontal 7-tap of channel sum
    __shared__ float sh_q[2][HR][LDSW];   // horizontal 7-tap of channel sumsq

    const int    tid  = threadIdx.x;
    const int    tx0  = blockIdx.x * TSX;
    const int    ty0  = blockIdx.y * TSY;
    const int    b    = blockIdx.z;
    const size_t plane = (size_t)H * W;
    const float4 z4 = make_float4(0.f, 0.f, 0.f, 0.f);

    const float* bp = pred + (size_t)b * 3 * plane;
    const float* bt = tgt  + (size_t)b * 3 * plane;

    // ---- Phase A: both inputs -> horizontal 7-tap -> LDS (one long
    //      load-rich stretch; each task's loads consumed in-iteration)
    for (int task = tid; task < NTASK; task += NT) {
        const int   w    = (task >= NTH) ? 1 : 0;
        const int   t0   = task - (w ? NTH : 0);
        const int   row  = t0 >> 4;                  // 0..21
        const int   cg   = t0 & 15;
        const int   gy   = ty0 - PAD + row;
        const float m    = ((unsigned)gy < (unsigned)H) ? 1.0f : 0.0f;
        const int   gyc  = min(max(gy, 0), H - 1);   // loads always legal
        const int   gx0  = tx0 + (cg << 2);
        const bool  lOK  = (gx0 > 0);
        const bool  rOK  = (gx0 < 508);

        const float* base = w ? bt : bp;
        const float* r0 = base + (size_t)gyc * W + gx0;
        const float* r1 = r0 + plane;
        const float* r2 = r1 + plane;

        T9 t;
        t.A0 = lOK ? ld4(r0 - 4) : z4;  t.B0 = ld4(r0);  t.C0 = rOK ? ld4(r0 + 4) : z4;
        t.A1 = lOK ? ld4(r1 - 4) : z4;  t.B1 = ld4(r1);  t.C1 = rOK ? ld4(r1 + 4) : z4;
        t.A2 = lOK ? ld4(r2 - 4) : z4;  t.B2 = ld4(r2);  t.C2 = rOK ? ld4(r2 + 4) : z4;

        float4 tl = add3(t.A0, t.A1, t.A2);
        float4 tm = add3(t.B0, t.B1, t.B2);
        float4 tr = add3(t.C0, t.C1, t.C2);
        float4 ul = sq3(t.A0, t.A1, t.A2);
        float4 um = sq3(t.B0, t.B1, t.B2);
        float4 ur = sq3(t.C0, t.C1, t.C2);

        float h0 = tl.y + tl.z + tl.w + tm.x + tm.y + tm.z + tm.w;
        float h1 = h0 - tl.y + tr.x;
        float h2 = h1 - tl.z + tr.y;
        float h3 = h2 - tl.w + tr.z;
        float g0 = ul.y + ul.z + ul.w + um.x + um.y + um.z + um.w;
        float g1 = g0 - ul.y + ur.x;
        float g2 = g1 - ul.z + ur.y;
        float g3 = g2 - ul.w + ur.z;

        *(float4*)&sh_s[w][row][cg << 2] =
            make_float4(h0 * m, h1 * m, h2 * m, h3 * m);
        *(float4*)&sh_q[w][row][cg << 2] =
            make_float4(g0 * m, g1 * m, g2 * m, g3 * m);
    }
    __syncthreads();   // the ONLY inter-phase barrier in the block

    // ---- Phase B: vertical 7-tap + std (both inputs) + fused smooth-L1
    float acc = 0.0f;
    {
        const int r  = tid >> 4;          // output row 0..15
        const int xo = (tid & 15) << 2;   // col offset

        float4 SP = z4, QP = z4, ST = z4, QT = z4;
        #pragma unroll
        for (int k = 0; k < K; ++k) {
            float4 a = *(const float4*)&sh_s[0][r + k][xo];
            float4 d = *(const float4*)&sh_q[0][r + k][xo];
            float4 e = *(const float4*)&sh_s[1][r + k][xo];
            float4 f = *(const float4*)&sh_q[1][r + k][xo];
            SP.x += a.x; SP.y += a.y; SP.z += a.z; SP.w += a.w;
            QP.x += d.x; QP.y += d.y; QP.z += d.z; QP.w += d.w;
            ST.x += e.x; ST.y += e.y; ST.z += e.z; ST.w += e.w;
            QT.x += f.x; QT.y += f.y; QT.z += f.z; QT.w += f.w;
        }

        #define LOSS1(sp, qp, st, qt)                                         \
            {                                                                 \
                float mup = (sp) * INV_N;                                     \
                float vp  = fmaf(-mup, mup, (qp) * INV_N);                    \
                float mut = (st) * INV_N;                                     \
                float vt  = fmaf(-mut, mut, (qt) * INV_N);                    \
                float d   = sqrtf(vp + 1e-8f) - sqrtf(vt + 1e-8f);            \
                float ad  = fabsf(d);                                         \
                acc += (ad < 1.0f) ? 0.5f * d * d : (ad - 0.5f);              \
            }
        LOSS1(SP.x, QP.x, ST.x, QT.x);
        LOSS1(SP.y, QP.y, ST.y, QT.y);
        LOSS1(SP.z, QP.z, ST.z, QT.z);
        LOSS1(SP.w, QP.w, ST.w, QT.w);
        #undef LOSS1
    }

    // ---- block reduction: wave64 shuffle, cross-wave via LDS, one atomic
    #pragma unroll
    for (int off = 32; off > 0; off >>= 1)
        acc += __shfl_down(acc, off, 64);

    __shared__ float wave_sums[NT / 64];
    if ((tid & 63) == 0) wave_sums[tid >> 6] = acc;
    __syncthreads();
    if (tid == 0) {
        float s = 0.0f;
        #pragma unroll
        for (int w = 0; w < NT / 64; ++w) s += wave_sums[w];
        atomicAdd(out, s * INV_TOTAL);
    }
}

extern "C" void kernel_launch(void* const* d_in, const int* in_sizes, int n_in,
                              void* d_out, int out_size, void* d_ws, size_t ws_size,
                              hipStream_t stream) {
    const float* pred = (const float*)d_in[0];
    const float* tgt  = (const float*)d_in[1];
    float* out = (float*)d_out;

    hipMemsetAsync(out, 0, sizeof(float), stream);

    // 8 colstrips x 32 rowstrips x 16 batches = 4096 short-lived blocks
    dim3 grid(512 / TSX, 512 / TSY, 16);
    dist_loss_kernel<<<grid, NT, 0, stream>>>(pred, tgt, out);
}